// Round 10
// baseline (405.463 us; speedup 1.0000x reference)
//
#include <hip/hip_runtime.h>

typedef _Float16 f16;
typedef _Float16 f16x8 __attribute__((ext_vector_type(8)));
typedef float f32x4 __attribute__((ext_vector_type(4)));

#define LDS_GL16(g, l) __builtin_amdgcn_global_load_lds( \
    (const __attribute__((address_space(1))) void*)(g),  \
    (__attribute__((address_space(3))) void*)(l), 16, 0, 0)
#define VMCNT(N) asm volatile("s_waitcnt vmcnt(" #N ")" ::: "memory")
#define BAR() __builtin_amdgcn_s_barrier()

// ---- fused prep: f32->f16 converts (4 bufs) + RMSNorm, one launch ---------
__global__ __launch_bounds__(256) void prep_kern(
        const float* __restrict__ qw,   f16* __restrict__ qwh,
        const float* __restrict__ kvw,  f16* __restrict__ kvwh,
        const float* __restrict__ outw, f16* __restrict__ outwh,
        const float* __restrict__ hid,  f16* __restrict__ hidh,
        const float* __restrict__ x, const float* __restrict__ lnsc,
        f16* __restrict__ xnh) {
    int b = blockIdx.x;
    if (b >= 16384) {   // RMSNorm row
        long base = (long)(b - 16384) * 2048 + threadIdx.x * 8;
        float4 a = *(const float4*)(x + base);
        float4 v = *(const float4*)(x + base + 4);
        float ss = a.x*a.x + a.y*a.y + a.z*a.z + a.w*a.w
                 + v.x*v.x + v.y*v.y + v.z*v.z + v.w*v.w;
        #pragma unroll
        for (int d = 1; d < 64; d <<= 1) ss += __shfl_xor(ss, d, 64);
        __shared__ float red[4];
        if ((threadIdx.x & 63) == 0) red[threadIdx.x >> 6] = ss;
        __syncthreads();
        ss = red[0] + red[1] + red[2] + red[3];
        float inv = 1.0f / (sqrtf(ss * (1.0f / 2048.0f)) + 1e-8f);
        int c = threadIdx.x * 8;
        float4 s1 = *(const float4*)(lnsc + c);
        float4 s2 = *(const float4*)(lnsc + c + 4);
        f16x8 o = { (f16)(a.x*inv*s1.x),(f16)(a.y*inv*s1.y),(f16)(a.z*inv*s1.z),(f16)(a.w*inv*s1.w),
                    (f16)(v.x*inv*s2.x),(f16)(v.y*inv*s2.y),(f16)(v.z*inv*s2.z),(f16)(v.w*inv*s2.w) };
        *(f16x8*)(xnh + base) = o;
        return;
    }
    const float* in; f16* out; long base;
    if (b < 2048)       { in = qw;   out = qwh;   base = (long)b * 2048; }
    else if (b < 6144)  { in = kvw;  out = kvwh;  base = (long)(b - 2048) * 2048; }
    else if (b < 8192)  { in = outw; out = outwh; base = (long)(b - 6144) * 2048; }
    else                { in = hid;  out = hidh;  base = (long)(b - 8192) * 2048; }
    long o = base + threadIdx.x * 8;
    float4 a = *(const float4*)(in + o);
    float4 c = *(const float4*)(in + o + 4);
    f16x8 v = { (f16)a.x,(f16)a.y,(f16)a.z,(f16)a.w,
                (f16)c.x,(f16)c.y,(f16)c.z,(f16)c.w };
    *(f16x8*)(out + o) = v;
}

// ---- GEMM 256x256 tile, 4 waves (2x2, 128x128/wave), BK=64, 8-phase -------
// Frag prefetch one phase ahead; 1 barrier/phase; VMCNT(16) each phase end.
// Regions (16KB each): A0 = A rows {0-63,128-191}, A1 = +64; B0/B1 likewise.
// Stage->read lead = 5 phases.  LDS: A[2] at 0/32KB, B[2] at 64KB/96KB.
template<int EPI>
__device__ __forceinline__ void gemm256_body(
        const f16* __restrict__ A, const f16* __restrict__ B,
        f16* __restrict__ Ch, float* __restrict__ Cf,
        const float* __restrict__ resid, int N, int Kd, int m0, int n0) {
    alignas(16) __shared__ f16 lds[65536];
    int tid = threadIdx.x, lane = tid & 63;
    int wid = tid >> 6, wm = wid >> 1, wn = wid & 1;
    int lr = lane & 15, g = lane >> 4;

    long gA[4], gB[4]; int dL[4];
    #pragma unroll
    for (int ld = 0; ld < 4; ++ld) {
        int idx = ld * 256 + tid;
        int sub = idx >> 3, c8 = idx & 7;
        int row = (sub & 63) + ((sub >> 6) << 7);   // {0-63,128-191}
        gA[ld] = (long)(m0 + row) * Kd + ((c8 ^ (row & 7)) << 3);
        gB[ld] = (long)(n0 + row) * Kd + ((c8 ^ (row & 7)) << 3);
        dL[ld] = row * 64 + c8 * 8;
    }
    long rowskip = (long)64 * Kd;
    auto stage = [&](int kt, int p, int r) {
        #pragma unroll
        for (int ld = 0; ld < 4; ++ld) {
            if (r == 0)      LDS_GL16(A + gA[ld] + kt * 64,           lds + p * 16384 + dL[ld]);
            else if (r == 3) LDS_GL16(A + gA[ld] + rowskip + kt * 64, lds + p * 16384 + dL[ld] + 4096);
            else if (r == 1) LDS_GL16(B + gB[ld] + kt * 64,           lds + 32768 + p * 16384 + dL[ld]);
            else             LDS_GL16(B + gB[ld] + rowskip + kt * 64, lds + 32768 + p * 16384 + dL[ld] + 4096);
        }
    };

    const char* ldsc = (const char*)lds;
    int swz = lr & 7;
    const char* baseA[2], *baseB[2];
    baseA[0] = ldsc + (wm * 128 + lr) * 128 + ((g ^ swz) << 4);
    baseA[1] = ldsc + (wm * 128 + lr) * 128 + (((4 + g) ^ swz) << 4);
    baseB[0] = ldsc + 65536 + (wn * 128 + lr) * 128 + ((g ^ swz) << 4);
    baseB[1] = ldsc + 65536 + (wn * 128 + lr) * 128 + (((4 + g) ^ swz) << 4);

    f32x4 acc[8][8] = {};
    f16x8 a0f[4][2], a1f[4][2], b0e[4][2], b0o[4][2], b1f[4][2];

    auto loadF = [&](f16x8 (&d)[4][2], const char* const (&bs)[2], int bufB, int q) {
        #pragma unroll
        for (int f = 0; f < 4; ++f)
            #pragma unroll
            for (int kk = 0; kk < 2; ++kk)
                d[f][kk] = *(const f16x8*)(bs[kk] + bufB + q * 8192 + f * 2048);
    };
    auto mma = [&](f16x8 (&aa)[4][2], f16x8 (&bb)[4][2], int qm, int qn) {
        __builtin_amdgcn_s_setprio(1);
        #pragma unroll
        for (int kk = 0; kk < 2; ++kk)
            #pragma unroll
            for (int mf = 0; mf < 4; ++mf)
                #pragma unroll
                for (int nf = 0; nf < 4; ++nf)
                    acc[qm * 4 + mf][qn * 4 + nf] = __builtin_amdgcn_mfma_f32_16x16x32_f16(
                        aa[mf][kk], bb[nf][kk], acc[qm * 4 + mf][qn * 4 + nf], 0, 0, 0);
        __builtin_amdgcn_s_setprio(0);
    };

    int NT = Kd >> 6, NI = NT >> 1;

    // prologue: t0 all 4 regions (buf0), t1 A0,B0,B1 (buf1)
    stage(0, 0, 0); stage(0, 0, 1); stage(0, 0, 2); stage(0, 0, 3);
    stage(1, 1, 0); stage(1, 1, 1); stage(1, 1, 2);
    VMCNT(12); BAR();                 // t0 landed; t1 x3 in flight
    loadF(a0f, baseA, 0, 0);          // t0 A-half0
    loadF(b0e, baseB, 0, 0);          // t0 B-half0

    for (int it = 0; it < NI - 1; ++it) {
        int t0 = it * 2;
        // p1: mma t0 q(0,0); prefetch b1f<-t0.B1
        loadF(b1f, baseB, 0, 1);
        stage(t0 + 1, 1, 3);
        VMCNT(16); BAR();
        mma(a0f, b0e, 0, 0);
        // p2: prefetch a1f<-t0.A1
        loadF(a1f, baseA, 0, 1);
        stage(t0 + 2, 0, 0);
        VMCNT(16); BAR();
        mma(a0f, b1f, 0, 1);
        // p3: prefetch a0f<-t1.A0
        loadF(a0f, baseA, 32768, 0);
        stage(t0 + 2, 0, 1);
        VMCNT(16); BAR();
        mma(a1f, b1f, 1, 1);
        // p4: prefetch b0o<-t1.B0
        loadF(b0o, baseB, 32768, 0);
        stage(t0 + 2, 0, 2);
        VMCNT(16); BAR();
        mma(a1f, b0e, 1, 0);
        // p5: mma t1 q(0,0); prefetch b1f<-t1.B1
        loadF(b1f, baseB, 32768, 1);
        stage(t0 + 2, 0, 3);
        VMCNT(16); BAR();
        mma(a0f, b0o, 0, 0);
        // p6: prefetch a1f<-t1.A1
        loadF(a1f, baseA, 32768, 1);
        stage(t0 + 3, 1, 0);
        VMCNT(16); BAR();
        mma(a0f, b1f, 0, 1);
        // p7: prefetch a0f<-t2.A0 (buf0)
        loadF(a0f, baseA, 0, 0);
        stage(t0 + 3, 1, 1);
        VMCNT(16); BAR();
        mma(a1f, b1f, 1, 1);
        // p8: prefetch b0e<-t2.B0
        loadF(b0e, baseB, 0, 0);
        stage(t0 + 3, 1, 2);
        VMCNT(16); BAR();
        mma(a1f, b0o, 1, 0);
    }
    {   // final iteration (t0 = NT-2, t1 = NT-1)
        loadF(b1f, baseB, 0, 1);
        stage(NT - 1, 1, 3);
        VMCNT(16); BAR();
        mma(a0f, b0e, 0, 0);
        loadF(a1f, baseA, 0, 1);
        VMCNT(12); BAR();
        mma(a0f, b1f, 0, 1);
        loadF(a0f, baseA, 32768, 0);
        VMCNT(8); BAR();
        mma(a1f, b1f, 1, 1);
        loadF(b0o, baseB, 32768, 0);
        VMCNT(4); BAR();
        mma(a1f, b0e, 1, 0);
        loadF(b1f, baseB, 32768, 1);
        VMCNT(0); BAR();
        mma(a0f, b0o, 0, 0);
        loadF(a1f, baseA, 32768, 1);
        BAR();
        mma(a0f, b1f, 0, 1);
        mma(a1f, b1f, 1, 1);
        mma(a1f, b0o, 1, 0);
    }

    // ---- epilogue: LDS bounce (XOR de-conflict) -> coalesced stores ----
    __syncthreads();
    if (EPI == 0) {
        #pragma unroll
        for (int i = 0; i < 8; ++i)
            #pragma unroll
            for (int j = 0; j < 8; ++j)
                #pragma unroll
                for (int reg = 0; reg < 4; ++reg) {
                    int row = wm * 128 + i * 16 + g * 4 + reg;
                    int col = (wn * 128 + j * 16 + lr) ^ ((row & 12) << 2);
                    lds[row * 256 + col] = (f16)acc[i][j][reg];
                }
        __syncthreads();
        #pragma unroll
        for (int k = 0; k < 32; ++k) {
            int e = k * 2048 + tid * 8;          // f16 elem in [256][256]
            int row = e >> 8, col = e & 255;
            *(f16x8*)(Ch + (long)(m0 + row) * N + n0 + col) =
                *(const f16x8*)(lds + row * 256 + (col ^ ((row & 12) << 2)));
        }
    } else {
        float* Ct = (float*)lds;                 // [128][256] f32 per pass
        #pragma unroll
        for (int h = 0; h < 2; ++h) {
            if (h) __syncthreads();
            if (wm == h) {
                #pragma unroll
                for (int i = 0; i < 8; ++i)
                    #pragma unroll
                    for (int j = 0; j < 8; ++j)
                        #pragma unroll
                        for (int reg = 0; reg < 4; ++reg) {
                            int row = i * 16 + g * 4 + reg;
                            int col = (wn * 128 + j * 16 + lr) ^ ((row & 4) << 2);
                            Ct[row * 256 + col] = acc[i][j][reg];
                        }
            }
            __syncthreads();
            #pragma unroll
            for (int k = 0; k < 16; ++k) {
                int e = k * 2048 + tid * 8;      // f32 elem in [128][256]
                int row = e >> 8, col = e & 255;
                int pc = col ^ ((row & 4) << 2);
                long gi = (long)(m0 + h * 128 + row) * N + n0 + col;
                float4 c0 = *(const float4*)(Ct + row * 256 + pc);
                float4 c1 = *(const float4*)(Ct + row * 256 + pc + 4);
                float4 r0 = *(const float4*)(resid + gi);
                float4 r1 = *(const float4*)(resid + gi + 4);
                c0.x += r0.x; c0.y += r0.y; c0.z += r0.z; c0.w += r0.w;
                c1.x += r1.x; c1.y += r1.y; c1.z += r1.z; c1.w += r1.w;
                *(float4*)(Cf + gi) = c0;
                *(float4*)(Cf + gi + 4) = c1;
            }
        }
    }
}

// ---- merged q+kv projection: grid 768 (q: 256 blocks, kv: 512 blocks) -----
__global__ __launch_bounds__(256, 1) void gemm_qkv(
        const f16* __restrict__ Aq, const f16* __restrict__ Bq, f16* __restrict__ Cq,
        const f16* __restrict__ Akv, const f16* __restrict__ Bkv, f16* __restrict__ Ckv) {
    int fid = (blockIdx.x & 7) * 96 + (blockIdx.x >> 3);   // XCD swizzle, 768 = 8*96
    const f16 *A, *B; f16* C; int N, lf, sh;
    if (fid < 256) { A = Aq;  B = Bq;  C = Cq;  N = 2048; lf = fid;       sh = 3; }
    else           { A = Akv; B = Bkv; C = Ckv; N = 4096; lf = fid - 256; sh = 4; }
    int by = lf >> sh, bx = lf & ((1 << sh) - 1);
    gemm256_body<0>(A, B, C, nullptr, nullptr, N, 2048, by << 8, bx << 8);
}

// ---- output projection + residual: grid 256 ----
__global__ __launch_bounds__(256, 1) void gemm_out(
        const f16* __restrict__ A, const f16* __restrict__ B,
        float* __restrict__ Cf, const float* __restrict__ resid) {
    int fid = (blockIdx.x & 7) * 32 + (blockIdx.x >> 3);   // 256 = 8*32
    int by = fid >> 3, bx = fid & 7;
    gemm256_body<1>(A, B, nullptr, Cf, resid, 2048, 2048, by << 8, bx << 8);
}

// ---------------- Attention: one block per (b,l,k,h) -----------------------
__global__ __launch_bounds__(256, 2) void attn_kern(
        const f16* __restrict__ Q,    // [8192, 2048]
        const f16* __restrict__ KV,   // [8192, 4096]  (k | v)
        const float* __restrict__ mask,      // [64*128]
        const float* __restrict__ bias,      // [32*16]
        float* __restrict__ attn_out,        // (B,L,K,H,R,M) f32
        f16* __restrict__ pv_out) {          // [8192, 2048]
    __shared__ f16 Vt[128 * 128];
    __shared__ f16 P[64 * 136];
    int blk = blockIdx.x;
    int h  = blk & 15;
    int bk = blk >> 4;
    int bl = bk >> 1;
    int tid = threadIdx.x, lane = tid & 63, w = tid >> 6;
    int r0 = w << 4;
    int lr = lane & 15, g = lane >> 4;
    long qbase  = (long)bk * 64 * 2048;
    long kvbase = (long)bl * 128 * 4096;
    f16x8 vreg[8];
    const f16* vsrc = KV + kvbase + 2048 + h * 128;
    #pragma unroll
    for (int rnd = 0; rnd < 8; ++rnd) {
        int idx = tid + rnd * 256;
        vreg[rnd] = *(const f16x8*)(vsrc + (long)(idx >> 4) * 4096 + (idx & 15) * 8);
    }
    f16x8 aq[4];
    const f16* qrow = Q + qbase + (long)(r0 + lr) * 2048 + h * 128 + g * 8;
    #pragma unroll
    for (int t4 = 0; t4 < 4; ++t4) aq[t4] = *(const f16x8*)(qrow + t4 * 32);
    f32x4 s[8] = {};
    const f16* kbase = KV + kvbase + h * 128 + g * 8;
    #pragma unroll
    for (int j = 0; j < 8; ++j) {
        #pragma unroll
        for (int t4 = 0; t4 < 4; ++t4) {
            f16x8 bkf = *(const f16x8*)(kbase + (long)(j * 16 + lr) * 4096 + t4 * 32);
            s[j] = __builtin_amdgcn_mfma_f32_16x16x32_f16(aq[t4], bkf, s[j], 0, 0, 0);
        }
    }
    float madd[8];
    #pragma unroll
    for (int j = 0; j < 8; ++j)
        madd[j] = (1.0f - mask[(long)bl * 128 + j * 16 + lr]) * -10000.0f;
    #pragma unroll
    for (int reg = 0; reg < 4; ++reg) {
        int r = r0 + g * 4 + reg;
        float mx = -3.0e38f;
        #pragma unroll
        for (int j = 0; j < 8; ++j) {
            int m = j * 16 + lr;
            int rel = m - r;
            int bkt = (rel < -15 ? -15 : (rel > 16 ? 16 : rel)) + 15;
            float v = s[j][reg] + bias[bkt * 16 + h] + madd[j];
            s[j][reg] = v;
            mx = fmaxf(mx, v);
        }
        #pragma unroll
        for (int d = 1; d < 16; d <<= 1) mx = fmaxf(mx, __shfl_xor(mx, d, 64));
        float sum = 0.0f;
        #pragma unroll
        for (int j = 0; j < 8; ++j) {
            float e = __expf(s[j][reg] - mx);
            s[j][reg] = e;
            sum += e;
        }
        #pragma unroll
        for (int d = 1; d < 16; d <<= 1) sum += __shfl_xor(sum, d, 64);
        float inv = 1.0f / sum;
        #pragma unroll
        for (int j = 0; j < 8; ++j) s[j][reg] *= inv;
    }
    long abase = (long)blk * 64 * 128;
    #pragma unroll
    for (int reg = 0; reg < 4; ++reg) {
        int r = r0 + g * 4 + reg;
        #pragma unroll
        for (int j = 0; j < 8; ++j) {
            attn_out[abase + (long)r * 128 + j * 16 + lr] = s[j][reg];
            P[r * 136 + j * 16 + lr] = (f16)s[j][reg];
        }
    }
    {
        char* vtb = (char*)Vt;
        #pragma unroll
        for (int rnd = 0; rnd < 8; ++rnd) {
            int idx = tid + rnd * 256;
            int k = idx >> 4, c0 = (idx & 15) * 8;
            #pragma unroll
            for (int i = 0; i < 8; ++i) {
                int c = c0 + i;
                int sx = ((c >> 3) ^ i) & 7;
                *(f16*)(vtb + c * 256 + ((k * 2) ^ (sx << 4))) = vreg[rnd][i];
            }
        }
    }
    __syncthreads();
    f16x8 pa[4];
    #pragma unroll
    for (int t4 = 0; t4 < 4; ++t4)
        pa[t4] = *(const f16x8*)(P + (r0 + lr) * 136 + t4 * 32 + g * 8);
    f32x4 o[8] = {};
    const char* vtb = (const char*)Vt;
    #pragma unroll
    for (int dj = 0; dj < 8; ++dj) {
        int c = dj * 16 + lr;
        int sc = (((c >> 3) ^ (c & 7)) & 7) << 4;
        const char* vrow = vtb + c * 256;
        #pragma unroll
        for (int t4 = 0; t4 < 4; ++t4) {
            f16x8 bv = *(const f16x8*)(vrow + ((t4 * 64 + g * 16) ^ sc));
            o[dj] = __builtin_amdgcn_mfma_f32_16x16x32_f16(pa[t4], bv, o[dj], 0, 0, 0);
        }
    }
    __syncthreads();
    #pragma unroll
    for (int dj = 0; dj < 8; ++dj)
        #pragma unroll
        for (int reg = 0; reg < 4; ++reg) {
            int row = r0 + g * 4 + reg;
            int col = (dj * 16 + lr) ^ ((row & 12) << 2);
            Vt[row * 128 + col] = (f16)o[dj][reg];
        }
    __syncthreads();
    f16* ob = pv_out + qbase + h * 128;
    #pragma unroll
    for (int k = 0; k < 4; ++k) {
        int e = k * 2048 + tid * 8;
        int row = e >> 7, col = e & 127;
        *(f16x8*)(ob + (long)row * 2048 + col) =
            *(const f16x8*)(Vt + row * 128 + (col ^ ((row & 12) << 2)));
    }
}

extern "C" void kernel_launch(void* const* d_in, const int* in_sizes, int n_in,
                              void* d_out, int out_size, void* d_ws, size_t ws_size,
                              hipStream_t stream) {
    const float* x     = (const float*)d_in[0];
    const float* hid   = (const float*)d_in[1];
    const float* mask  = (const float*)d_in[2];
    const float* lnsc  = (const float*)d_in[3];
    const float* q_w   = (const float*)d_in[4];
    const float* kv_w  = (const float*)d_in[5];
    const float* out_w = (const float*)d_in[6];
    const float* bias  = (const float*)d_in[7];
    float* out0 = (float*)d_out;             // (B,L,K,R,Dm) = 16,777,216 f32
    float* attn = out0 + 16777216;           // (B,L,K,H,R,M) = 16,777,216 f32

    f16* kv_h  = (f16*)out0;                 // dead until final GEMM
    f16* xn_h  = (f16*)attn;                 // dead until attn_kern writes attn
    f16* hid_h = (f16*)(attn + 8388608);
    char* ws = (char*)d_ws;
    f16* q_h    = (f16*)(ws);                 // 32 MiB
    f16* ao_h   = (f16*)(ws + 33554432L);     // 32 MiB
    f16* qw_h   = (f16*)(ws + 67108864L);     //  8 MiB
    f16* kvw_h  = (f16*)(ws + 75497472L);     // 16 MiB
    f16* outw_h = (f16*)(ws + 92274688L);     //  8 MiB -> 96 MiB total

    prep_kern<<<24576, 256, 0, stream>>>(q_w, qw_h, kv_w, kvw_h,
                                         out_w, outw_h, hid, hid_h,
                                         x, lnsc, xn_h);
    gemm_qkv<<<768, 256, 0, stream>>>(xn_h, qw_h, q_h, hid_h, kvw_h, kv_h);
    attn_kern<<<2048, 256, 0, stream>>>(q_h, kv_h, mask, bias, attn, ao_h);
    gemm_out<<<256, 256, 0, stream>>>(ao_h, outw_h, out0, x);
}